// Round 5
// baseline (389.758 us; speedup 1.0000x reference)
//
#include <hip/hip_runtime.h>
#include <math.h>

#define N_ROWS 32768
#define DIM    1024
#define NE     64
#define KTOP   8

// v6: hybrid operand delivery. v5 (148us) was LDS-pipe-bound: 48 LDS-cyc per
// 128 FMA-cyc per q-step; one LDS per 4 SIMDs => 1.5x over the FMA floor
// (41us LDS floor) + unpipelined ds latency. v6 moves the x fragment to
// direct VMEM (row-major b128, 8-lane same-address dedup, L1 line reuse;
// HBM traffic unchanged - the frags ARE the x stream) and keeps only w in
// LDS (2 broadcast b128/q = 24 LDS-cyc per 128 FMA-cyc -> LDS now under FMA
// capacity). wf reads are explicitly double-buffered (static wf0/wf1) to
// hide ds latency under the previous q's 128-cyc FMA block.
// Waves own contiguous 128-k ranges; LDS slices stay per-wave private ->
// zero barriers in the main loop. Spill discipline (v3/v4 lessons): every
// register array index is a compile-time constant; q-loop fully unrolled
// via macros; k-chunked so live set = acc64 + xA32 + wf16 + pw8 + addr < 128
// (__launch_bounds__(512,4) enforces the cap; WRITE_SIZE is the spill canary).
// Reduction + epilogue are the v5-verified code, byte-identical.

#define LOADW(DST, Q) do {                                              \
    *(float4*)((DST) + 0) = *(const float4*)(ws + (Q) * 64 + er8 + 0);  \
    *(float4*)((DST) + 4) = *(const float4*)(ws + (Q) * 64 + er8 + 4);  \
} while (0)

#define FMAQ(W, Q) do {                                                 \
    _Pragma("unroll")                                                   \
    for (int m_ = 0; m_ < 8; ++m_) {                                    \
        const float xv_ = xA[m_ * 4 + ((Q) & 3)];                       \
        _Pragma("unroll")                                               \
        for (int n_ = 0; n_ < 8; ++n_)                                  \
            acc[m_][n_] = fmaf(xv_, (W)[n_], acc[m_][n_]);              \
    }                                                                   \
} while (0)

extern "C" __global__ void __launch_bounds__(512, 4)
moe_gate_kernel(const float* __restrict__ x, const float* __restrict__ gw,
                const float* __restrict__ nw, const float* __restrict__ noise,
                float* __restrict__ out0, float* __restrict__ out1,
                float* __restrict__ lossp,
                double* __restrict__ esum, int* __restrict__ ticket) {
    __shared__ __align__(16) float smem[8256];   // 33,024 B
    __shared__ int isLast;
    float* wt  = smem;          // main loop: [8 wid][8 q][64 e] private slices
    float* red = smem;          // overlay after the post-loop barrier [4096]
    float* lg  = smem + 4096;   // logits [64*65]

    const int tid  = threadIdx.x;
    const int lane = tid & 63;
    const int wid  = __builtin_amdgcn_readfirstlane(tid >> 6);   // 0..7
    const int er   = lane >> 3;       // expert-group: experts er*8 + n
    const int rr   = lane & 7;        // row-group:    rows    rr*8 + m
    const int er8  = er * 8;
    const int rr8  = rr * 8;
    const int row0 = blockIdx.x * 64;
    const int kwb  = wid * 128;       // wave's contiguous k-range

    float acc[8][8];
#pragma unroll
    for (int m = 0; m < 8; ++m)
#pragma unroll
        for (int n = 0; n < 8; ++n) acc[m][n] = 0.f;

    // w staging: thread (wid,lane) loads gw[lane][kwb + rnd*8 .. +8] and
    // writes its wave's slice k-major: ws[q*64 + lane].
    const float* gwp = gw + (size_t)lane * DIM + kwb;
    float* ws = wt + wid * 512;       // wave-private 2 KB slice
    float* ww = ws + lane;            // + q*64
    // x fragment offset (floats): per-lane row base + wave k base.
    const int voff = (row0 + rr8) * DIM + kwb;

    float xA[32], wf0[8], wf1[8];

#pragma unroll 1
    for (int rnd = 0; rnd < 16; ++rnd) {
        const int kof = rnd * 8;
        // ---- stage this round's w slice (private -> no barrier) ----
        float pw[8];
        *(float4*)(pw + 0) = *(const float4*)(gwp + kof + 0);
        *(float4*)(pw + 4) = *(const float4*)(gwp + kof + 4);
#pragma unroll
        for (int q = 0; q < 8; ++q) ww[q * 64] = pw[q];   // lane-consecutive: free

        // ---- x half A: rows rr8+m, k = kwb+kof+0..3 (8x b128 VMEM) ----
#pragma unroll
        for (int m = 0; m < 8; ++m)
            *(float4*)(xA + 4 * m) = *(const float4*)(x + m * DIM + voff + kof);

        LOADW(wf0, 0);
        LOADW(wf1, 1);  FMAQ(wf0, 0);
        LOADW(wf0, 2);  FMAQ(wf1, 1);
        LOADW(wf1, 3);  FMAQ(wf0, 2);
                        FMAQ(wf1, 3);

        // ---- x half B: k = kwb+kof+4..7 (reuses xA storage) ----
#pragma unroll
        for (int m = 0; m < 8; ++m)
            *(float4*)(xA + 4 * m) = *(const float4*)(x + m * DIM + voff + kof + 4);

        LOADW(wf0, 4);
        LOADW(wf1, 5);  FMAQ(wf0, 4);
        LOADW(wf0, 6);  FMAQ(wf1, 5);
        LOADW(wf1, 7);  FMAQ(wf0, 6);
                        FMAQ(wf1, 7);
    }

    // ---- k-split reduction over the 8 waves (v5-verified, verbatim) ----
    __syncthreads();                  // all waves done with wt
#pragma unroll
    for (int s = 0; s < 8; ++s) {     // row = rr*8 + s
        float4 v0 = make_float4(acc[s][0], acc[s][1], acc[s][2], acc[s][3]);
        float4 v1 = make_float4(acc[s][4], acc[s][5], acc[s][6], acc[s][7]);
        *(float4*)(red + wid * 512 + rr * 64 + er8 + 0) = v0;
        *(float4*)(red + wid * 512 + rr * 64 + er8 + 4) = v1;
        __syncthreads();
        {
            const int r2 = tid >> 6, e = tid & 63;
            float t = 0.f;
#pragma unroll
            for (int w = 0; w < 8; ++w) t += red[w * 512 + r2 * 64 + e];
            lg[(r2 * 8 + s) * 65 + e] = t;   // row r2*8+s, expert e
        }
        __syncthreads();
    }

    // ---- epilogue: wave handles 8 rows, lane = expert (v0-proven code) ----
    const float nwl = nw[lane];
    float epart = 0.f;

#pragma unroll 1
    for (int i = 0; i < 8; ++i) {
        const int    lrow = wid * 8 + i;
        const size_t grow = (size_t)(row0 + lrow);
        const float  lgv  = lg[lrow * 65 + lane];

        // dense softmax over 64 experts (load-balance mean term)
        float m = lgv;
#pragma unroll
        for (int off = 32; off; off >>= 1) m = fmaxf(m, __shfl_xor(m, off));
        float p = __expf(lgv - m);
        float s = p;
#pragma unroll
        for (int off = 32; off; off >>= 1) s += __shfl_xor(s, off);
        epart += p / s;

        // noisy logits + iterative top-8 argmax (tie -> lower index)
        const float nz    = noise[grow * NE + lane];
        const float noisy = fmaf(nz, nwl, lgv);
        float cur  = noisy;
        bool  sel  = false;
        float mtop = 0.f;
        int   myid = 0;
#pragma unroll
        for (int j = 0; j < KTOP; ++j) {
            float v = cur; int id = lane;
#pragma unroll
            for (int off = 32; off; off >>= 1) {
                float ov = __shfl_xor(v, off);
                int   oi = __shfl_xor(id, off);
                if (ov > v || (ov == v && oi < id)) { v = ov; id = oi; }
            }
            if (j == 0) mtop = v;
            if (lane == id) { sel = true; cur = -INFINITY; }
            if (lane == j) myid = id;
        }

        float swv  = sel ? __expf(noisy - mtop) : 0.f;
        float ssum = swv;
#pragma unroll
        for (int off = 32; off; off >>= 1) ssum += __shfl_xor(ssum, off);

        out0[grow * NE + lane] = swv / ssum;                // coalesced 256 B/row
        if (lane < KTOP) out1[grow * KTOP + lane] = (float)myid;
    }

    // ---- load-balance sums: block partial -> device atomics ----
    __syncthreads();                   // lg reads done; reuse red
    red[wid * 64 + lane] = epart;
    __syncthreads();
    if (tid < NE) {
        float t = 0.f;
#pragma unroll
        for (int w = 0; w < 8; ++w) t += red[w * 64 + tid];
        atomicAdd(&esum[tid], (double)t);
        __threadfence();
    }
    __syncthreads();
    if (tid == 0) {
        int t = atomicAdd(ticket, 1);
        isLast = (t == (int)gridDim.x - 1);
        __threadfence();
    }
    __syncthreads();

    // ---- last block computes the scalar loss (f64) ----
    if (isLast && tid < NE) {
        double v = atomicAdd(&esum[tid], 0.0);    // device-scope read
        double mean = v * (1.0 / 32768.0);
        double d  = mean - (1.0 / 64.0);
        double sq = d * d;
#pragma unroll
        for (int off = 32; off; off >>= 1) sq += __shfl_xor(sq, off);
        if (tid == 0) lossp[0] = (float)(sq * (1.0 / 64.0) * 0.01);
    }
}

extern "C" void kernel_launch(void* const* d_in, const int* in_sizes, int n_in,
                              void* d_out, int out_size, void* d_ws, size_t ws_size,
                              hipStream_t stream) {
    const float* x     = (const float*)d_in[0];   // [32768,1024]
    const float* gw    = (const float*)d_in[1];   // [64,1024]
    const float* nw    = (const float*)d_in[2];   // [64]
    const float* noise = (const float*)d_in[3];   // [32768,64]

    float* out0  = (float*)d_out;                       // [32768,64] gated weights
    float* out1  = out0 + (size_t)N_ROWS * NE;          // [32768,8] ids as f32
    float* lossp = out1 + (size_t)N_ROWS * KTOP;        // scalar loss

    double* esum   = (double*)d_ws;                     // [64]
    int*    ticket = (int*)((char*)d_ws + 512);

    hipMemsetAsync(d_ws, 0, 520, stream);
    moe_gate_kernel<<<N_ROWS / 64, 512, 0, stream>>>(x, gw, nw, noise,
                                                     out0, out1, lossp, esum, ticket);
}

// Round 6
// 335.229 us; speedup vs baseline: 1.1627x; 1.1627x over previous
//
#include <hip/hip_runtime.h>
#include <math.h>

#define N_ROWS 32768
#define DIM    1024
#define NE     64
#define KTOP   8

// v7 = v5 (148us, all-LDS operand delivery, barrier-free main loop) + 3 fixes:
//  1) q-loop software pipeline: xf/wf double-buffered (static macro indices),
//     ds_reads of q+1 issued before FMAs of q -> DS latency hidden under the
//     128-cyc FMA block (v5's unroll-1 q loop exposed it every step).
//  2) cross-round VMEM prefetch: px/pw for rnd+1 issued right after this
//     round's ds_writes, consumed at next round's ds_writes -> ~900cyc HBM
//     latency (x is the cold stream) hides under ~1100cyc of FMAs. Same 16
//     regs (SSA; ds_write reads old value before global_load redefines).
//  3) reduction buffer stride 64 -> 68: v5/v6's identical 3.67M
//     SQ_LDS_BANK_CONFLICT proved the red b128 writes (start words 8er mod 32
//     = 4 values -> 16 banks) were the source; stride 68 spreads start words
//     over all 32 banks (4rr+8er mod 32) = 8-access/bank minimum.
// v6 lesson (250us): direct-VMEM x fragments = 64-line gather whose lines
// thrash L1 between rounds (FETCH 77->231MB) -> keep both operands in LDS.
// Spill discipline: all register-array indices compile-time; live set
// acc64 + xfwf32 + pxpw16 + addr ~= 124 <= 128 (v6: exactly 128, no spill).

#define LOADQ(XB, WB, Q) do {                                        \
    *(float4*)((XB) + 0) = *(const float4*)(rd_x + (Q) * 64 + 0);    \
    *(float4*)((XB) + 4) = *(const float4*)(rd_x + (Q) * 64 + 4);    \
    *(float4*)((WB) + 0) = *(const float4*)(rd_w + (Q) * 64 + 0);    \
    *(float4*)((WB) + 4) = *(const float4*)(rd_w + (Q) * 64 + 4);    \
} while (0)

#define FMAQ(XB, WB) do {                                            \
    _Pragma("unroll")                                                \
    for (int m_ = 0; m_ < 8; ++m_) {                                 \
        _Pragma("unroll")                                            \
        for (int n_ = 0; n_ < 8; ++n_)                               \
            acc[m_][n_] = fmaf((XB)[m_], (WB)[n_], acc[m_][n_]);     \
    }                                                                \
} while (0)

extern "C" __global__ void __launch_bounds__(512, 4)
moe_gate_kernel(const float* __restrict__ x, const float* __restrict__ gw,
                const float* __restrict__ nw, const float* __restrict__ noise,
                float* __restrict__ out0, float* __restrict__ out1,
                float* __restrict__ lossp,
                double* __restrict__ esum, int* __restrict__ ticket) {
    __shared__ __align__(16) float smem[8512];   // 34,048 B
    __shared__ int isLast;
    float* xt  = smem;          // [8 wid][8 q][64 row] private slices
    float* wt  = smem + 4096;   // [8 wid][8 q][64 e]   private slices
    float* red = smem;          // overlay: [8 wid][544] = wid*544 + rr*68 + e
    float* lg  = smem + 4352;   // overlay: logits [64*65]

    const int tid  = threadIdx.x;
    const int lane = tid & 63;
    const int wid  = __builtin_amdgcn_readfirstlane(tid >> 6);   // 0..7
    const int er   = lane >> 3;       // expert-group: experts er*8 + n
    const int rr   = lane & 7;        // row-group:    rows    rr*8 + m
    const int er8  = er * 8;
    const int rr8  = rr * 8;
    const int row0 = blockIdx.x * 64;
    const int kwb  = wid * 128;       // wave's contiguous k-range

    float acc[8][8];
#pragma unroll
    for (int m = 0; m < 8; ++m)
#pragma unroll
        for (int n = 0; n < 8; ++n) acc[m][n] = 0.f;

    // staging: thread (wid,lane) loads x[row0+lane][kwb+rnd*8..+8] and
    // gw[lane][kwb+rnd*8..+8]; writes k-major into its wave's private slices.
    const float* gx   = x  + (size_t)(row0 + lane) * DIM + kwb;
    const float* gwp  = gw + (size_t)lane * DIM + kwb;
    float*       ws_x = xt + wid * 512 + lane;     // + q*64
    float*       ws_w = wt + wid * 512 + lane;
    const float* rd_x = xt + wid * 512 + rr8;      // + q*64
    const float* rd_w = wt + wid * 512 + er8;

    float px[8], pw[8], xf0[8], xf1[8], wf0[8], wf1[8];
    // prologue: load rnd 0 (latency exposed once)
    *(float4*)(px + 0) = *(const float4*)(gx + 0);
    *(float4*)(px + 4) = *(const float4*)(gx + 4);
    *(float4*)(pw + 0) = *(const float4*)(gwp + 0);
    *(float4*)(pw + 4) = *(const float4*)(gwp + 4);

#pragma unroll 1
    for (int rnd = 0; rnd < 16; ++rnd) {
        // write this round's slice (vmcnt waited via px/pw register deps;
        // same-wave LDS is in-order vs last round's reads -> no barrier)
#pragma unroll
        for (int q = 0; q < 8; ++q) {      // lane-consecutive words: free
            ws_x[q * 64] = px[q];
            ws_w[q * 64] = pw[q];
        }
        if (rnd < 15) {                    // prefetch rnd+1 under the FMAs
            *(float4*)(px + 0) = *(const float4*)(gx + (rnd + 1) * 8 + 0);
            *(float4*)(px + 4) = *(const float4*)(gx + (rnd + 1) * 8 + 4);
            *(float4*)(pw + 0) = *(const float4*)(gwp + (rnd + 1) * 8 + 0);
            *(float4*)(pw + 4) = *(const float4*)(gwp + (rnd + 1) * 8 + 4);
        }
        // pipelined q-loop: reads of q+1 in flight during FMAs of q
        LOADQ(xf0, wf0, 0);
        LOADQ(xf1, wf1, 1);  FMAQ(xf0, wf0);
        LOADQ(xf0, wf0, 2);  FMAQ(xf1, wf1);
        LOADQ(xf1, wf1, 3);  FMAQ(xf0, wf0);
        LOADQ(xf0, wf0, 4);  FMAQ(xf1, wf1);
        LOADQ(xf1, wf1, 5);  FMAQ(xf0, wf0);
        LOADQ(xf0, wf0, 6);  FMAQ(xf1, wf1);
        LOADQ(xf1, wf1, 7);  FMAQ(xf0, wf0);
                             FMAQ(xf1, wf1);
    }

    // ---- k-split reduction over the 8 waves (stride-68: conflict-free) ----
    __syncthreads();                  // all waves done with xt/wt
#pragma unroll
    for (int s = 0; s < 8; ++s) {     // row = rr*8 + s
        float4 v0 = make_float4(acc[s][0], acc[s][1], acc[s][2], acc[s][3]);
        float4 v1 = make_float4(acc[s][4], acc[s][5], acc[s][6], acc[s][7]);
        *(float4*)(red + wid * 544 + rr * 68 + er8 + 0) = v0;
        *(float4*)(red + wid * 544 + rr * 68 + er8 + 4) = v1;
        __syncthreads();
        {
            const int r2 = tid >> 6, e = tid & 63;
            float t = 0.f;
#pragma unroll
            for (int w = 0; w < 8; ++w) t += red[w * 544 + r2 * 68 + e];
            lg[(r2 * 8 + s) * 65 + e] = t;   // row r2*8+s, expert e
        }
        __syncthreads();
    }

    // ---- epilogue: wave handles 8 rows, lane = expert (v0-proven code) ----
    const float nwl = nw[lane];
    float epart = 0.f;

#pragma unroll 1
    for (int i = 0; i < 8; ++i) {
        const int    lrow = wid * 8 + i;
        const size_t grow = (size_t)(row0 + lrow);
        const float  lgv  = lg[lrow * 65 + lane];

        // dense softmax over 64 experts (load-balance mean term)
        float m = lgv;
#pragma unroll
        for (int off = 32; off; off >>= 1) m = fmaxf(m, __shfl_xor(m, off));
        float p = __expf(lgv - m);
        float s = p;
#pragma unroll
        for (int off = 32; off; off >>= 1) s += __shfl_xor(s, off);
        epart += p / s;

        // noisy logits + iterative top-8 argmax (tie -> lower index)
        const float nz    = noise[grow * NE + lane];
        const float noisy = fmaf(nz, nwl, lgv);
        float cur  = noisy;
        bool  sel  = false;
        float mtop = 0.f;
        int   myid = 0;
#pragma unroll
        for (int j = 0; j < KTOP; ++j) {
            float v = cur; int id = lane;
#pragma unroll
            for (int off = 32; off; off >>= 1) {
                float ov = __shfl_xor(v, off);
                int   oi = __shfl_xor(id, off);
                if (ov > v || (ov == v && oi < id)) { v = ov; id = oi; }
            }
            if (j == 0) mtop = v;
            if (lane == id) { sel = true; cur = -INFINITY; }
            if (lane == j) myid = id;
        }

        float swv  = sel ? __expf(noisy - mtop) : 0.f;
        float ssum = swv;
#pragma unroll
        for (int off = 32; off; off >>= 1) ssum += __shfl_xor(ssum, off);

        out0[grow * NE + lane] = swv / ssum;                // coalesced 256 B/row
        if (lane < KTOP) out1[grow * KTOP + lane] = (float)myid;
    }

    // ---- load-balance sums: block partial -> device atomics ----
    __syncthreads();                   // lg reads done; reuse red
    red[wid * 64 + lane] = epart;
    __syncthreads();
    if (tid < NE) {
        float t = 0.f;
#pragma unroll
        for (int w = 0; w < 8; ++w) t += red[w * 64 + tid];
        atomicAdd(&esum[tid], (double)t);
        __threadfence();
    }
    __syncthreads();
    if (tid == 0) {
        int t = atomicAdd(ticket, 1);
        isLast = (t == (int)gridDim.x - 1);
        __threadfence();
    }
    __syncthreads();

    // ---- last block computes the scalar loss (f64) ----
    if (isLast && tid < NE) {
        double v = atomicAdd(&esum[tid], 0.0);    // device-scope read
        double mean = v * (1.0 / 32768.0);
        double d  = mean - (1.0 / 64.0);
        double sq = d * d;
#pragma unroll
        for (int off = 32; off; off >>= 1) sq += __shfl_xor(sq, off);
        if (tid == 0) lossp[0] = (float)(sq * (1.0 / 64.0) * 0.01);
    }
}

extern "C" void kernel_launch(void* const* d_in, const int* in_sizes, int n_in,
                              void* d_out, int out_size, void* d_ws, size_t ws_size,
                              hipStream_t stream) {
    const float* x     = (const float*)d_in[0];   // [32768,1024]
    const float* gw    = (const float*)d_in[1];   // [64,1024]
    const float* nw    = (const float*)d_in[2];   // [64]
    const float* noise = (const float*)d_in[3];   // [32768,64]

    float* out0  = (float*)d_out;                       // [32768,64] gated weights
    float* out1  = out0 + (size_t)N_ROWS * NE;          // [32768,8] ids as f32
    float* lossp = out1 + (size_t)N_ROWS * KTOP;        // scalar loss

    double* esum   = (double*)d_ws;                     // [64]
    int*    ticket = (int*)((char*)d_ws + 512);

    hipMemsetAsync(d_ws, 0, 520, stream);
    moe_gate_kernel<<<N_ROWS / 64, 512, 0, stream>>>(x, gw, nw, noise,
                                                     out0, out1, lossp, esum, ticket);
}

// Round 8
// 304.070 us; speedup vs baseline: 1.2818x; 1.1025x over previous
//
#include <hip/hip_runtime.h>
#include <math.h>

#define N_ROWS 32768
#define DIM    1024
#define NE     64
#define KTOP   8

// v9 = v5 (148us, proven structure) + the two VERIFIED v7 fixes only:
//  1) pipelined q-loop: xf/wf double-buffered (static indices), ds_reads of
//     q+1 in flight under FMAs of q (correct in v7).
//  2) stride-68 reduction buffer: v7 measured SQ_LDS_BANK_CONFLICT
//     3.67M -> 0 with this layout.
// REMOVED v7's cross-round px/pw prefetch: holding those 16 regs live across
// the q-loop spilled acc (WRITE 78MB, FETCH 300MB -> 190us). Staging load is
// back at round top (v5-style): px/pw are transient (load -> ds_write), never
// live across the q-loop. Peak live ~106 regs < 128 cap.
// REVERTED v8's global_load_lds(offset=q*4) staging: unverified imm-offset
// semantics produced garbage logits (ids absmax 63). If async staging returns
// it will use the v4-proven offset=0 form only.
// Main loop stays barrier-free: wave-private LDS slices, same-wave DS order.

#define LOADQ(XB, WB, Q) do {                                        \
    *(float4*)((XB) + 0) = *(const float4*)(rd_x + (Q) * 64 + 0);    \
    *(float4*)((XB) + 4) = *(const float4*)(rd_x + (Q) * 64 + 4);    \
    *(float4*)((WB) + 0) = *(const float4*)(rd_w + (Q) * 64 + 0);    \
    *(float4*)((WB) + 4) = *(const float4*)(rd_w + (Q) * 64 + 4);    \
} while (0)

#define FMAQ(XB, WB) do {                                            \
    _Pragma("unroll")                                                \
    for (int m_ = 0; m_ < 8; ++m_) {                                 \
        _Pragma("unroll")                                            \
        for (int n_ = 0; n_ < 8; ++n_)                               \
            acc[m_][n_] = fmaf((XB)[m_], (WB)[n_], acc[m_][n_]);     \
    }                                                                \
} while (0)

extern "C" __global__ void __launch_bounds__(512, 4)
moe_gate_kernel(const float* __restrict__ x, const float* __restrict__ gw,
                const float* __restrict__ nw, const float* __restrict__ noise,
                float* __restrict__ out0, float* __restrict__ out1,
                float* __restrict__ lossp,
                double* __restrict__ esum, int* __restrict__ ticket) {
    __shared__ __align__(16) float smem[8512];   // 34,048 B
    __shared__ int isLast;
    float* xt  = smem;          // [8 wid][8 q][64 row] private slices
    float* wt  = smem + 4096;   // [8 wid][8 q][64 e]   private slices
    float* red = smem;          // overlay: [8 wid][544] = wid*544 + rr*68 + e
    float* lg  = smem + 4352;   // overlay: logits [64*65]

    const int tid  = threadIdx.x;
    const int lane = tid & 63;
    const int wid  = __builtin_amdgcn_readfirstlane(tid >> 6);   // 0..7
    const int er   = lane >> 3;       // expert-group: experts er*8 + n
    const int rr   = lane & 7;        // row-group:    rows    rr*8 + m
    const int er8  = er * 8;
    const int rr8  = rr * 8;
    const int row0 = blockIdx.x * 64;
    const int kwb  = wid * 128;       // wave's contiguous k-range

    float acc[8][8];
#pragma unroll
    for (int m = 0; m < 8; ++m)
#pragma unroll
        for (int n = 0; n < 8; ++n) acc[m][n] = 0.f;

    // staging: thread (wid,lane) loads x[row0+lane][kwb+rnd*8..+8] and
    // gw[lane][kwb+rnd*8..+8]; writes k-major into its wave's private slices.
    const float* gx   = x  + (size_t)(row0 + lane) * DIM + kwb;
    const float* gwp  = gw + (size_t)lane * DIM + kwb;
    float*       ws_x = xt + wid * 512 + lane;     // + q*64
    float*       ws_w = wt + wid * 512 + lane;
    const float* rd_x = xt + wid * 512 + rr8;      // + q*64
    const float* rd_w = wt + wid * 512 + er8;

    float xf0[8], xf1[8], wf0[8], wf1[8];

#pragma unroll 1
    for (int rnd = 0; rnd < 16; ++rnd) {
        // ---- stage this round (px/pw transient: load -> ds_write, dead) ----
        {
            float px[8], pw[8];
            *(float4*)(px + 0) = *(const float4*)(gx  + rnd * 8 + 0);
            *(float4*)(px + 4) = *(const float4*)(gx  + rnd * 8 + 4);
            *(float4*)(pw + 0) = *(const float4*)(gwp + rnd * 8 + 0);
            *(float4*)(pw + 4) = *(const float4*)(gwp + rnd * 8 + 4);
#pragma unroll
            for (int q = 0; q < 8; ++q) {   // lane-consecutive words: free
                ws_x[q * 64] = px[q];
                ws_w[q * 64] = pw[q];
            }
        }
        // ---- pipelined q-loop: reads of q+1 in flight during FMAs of q ----
        LOADQ(xf0, wf0, 0);
        LOADQ(xf1, wf1, 1);  FMAQ(xf0, wf0);
        LOADQ(xf0, wf0, 2);  FMAQ(xf1, wf1);
        LOADQ(xf1, wf1, 3);  FMAQ(xf0, wf0);
        LOADQ(xf0, wf0, 4);  FMAQ(xf1, wf1);
        LOADQ(xf1, wf1, 5);  FMAQ(xf0, wf0);
        LOADQ(xf0, wf0, 6);  FMAQ(xf1, wf1);
        LOADQ(xf1, wf1, 7);  FMAQ(xf0, wf0);
                             FMAQ(xf1, wf1);
    }

    // ---- k-split reduction over the 8 waves (stride-68: conflict-free) ----
    __syncthreads();                  // all waves done with xt/wt
#pragma unroll
    for (int s = 0; s < 8; ++s) {     // row = rr*8 + s
        float4 v0 = make_float4(acc[s][0], acc[s][1], acc[s][2], acc[s][3]);
        float4 v1 = make_float4(acc[s][4], acc[s][5], acc[s][6], acc[s][7]);
        *(float4*)(red + wid * 544 + rr * 68 + er8 + 0) = v0;
        *(float4*)(red + wid * 544 + rr * 68 + er8 + 4) = v1;
        __syncthreads();
        {
            const int r2 = tid >> 6, e = tid & 63;
            float t = 0.f;
#pragma unroll
            for (int w = 0; w < 8; ++w) t += red[w * 544 + r2 * 68 + e];
            lg[(r2 * 8 + s) * 65 + e] = t;   // row r2*8+s, expert e
        }
        __syncthreads();
    }

    // ---- epilogue: wave handles 8 rows, lane = expert (v0-proven code) ----
    const float nwl = nw[lane];
    float epart = 0.f;

#pragma unroll 1
    for (int i = 0; i < 8; ++i) {
        const int    lrow = wid * 8 + i;
        const size_t grow = (size_t)(row0 + lrow);
        const float  lgv  = lg[lrow * 65 + lane];

        // dense softmax over 64 experts (load-balance mean term)
        float m = lgv;
#pragma unroll
        for (int off = 32; off; off >>= 1) m = fmaxf(m, __shfl_xor(m, off));
        float p = __expf(lgv - m);
        float s = p;
#pragma unroll
        for (int off = 32; off; off >>= 1) s += __shfl_xor(s, off);
        epart += p / s;

        // noisy logits + iterative top-8 argmax (tie -> lower index)
        const float nz    = noise[grow * NE + lane];
        const float noisy = fmaf(nz, nwl, lgv);
        float cur  = noisy;
        bool  sel  = false;
        float mtop = 0.f;
        int   myid = 0;
#pragma unroll
        for (int j = 0; j < KTOP; ++j) {
            float v = cur; int id = lane;
#pragma unroll
            for (int off = 32; off; off >>= 1) {
                float ov = __shfl_xor(v, off);
                int   oi = __shfl_xor(id, off);
                if (ov > v || (ov == v && oi < id)) { v = ov; id = oi; }
            }
            if (j == 0) mtop = v;
            if (lane == id) { sel = true; cur = -INFINITY; }
            if (lane == j) myid = id;
        }

        float swv  = sel ? __expf(noisy - mtop) : 0.f;
        float ssum = swv;
#pragma unroll
        for (int off = 32; off; off >>= 1) ssum += __shfl_xor(ssum, off);

        out0[grow * NE + lane] = swv / ssum;                // coalesced 256 B/row
        if (lane < KTOP) out1[grow * KTOP + lane] = (float)myid;
    }

    // ---- load-balance sums: block partial -> device atomics ----
    __syncthreads();                   // lg reads done; reuse red
    red[wid * 64 + lane] = epart;
    __syncthreads();
    if (tid < NE) {
        float t = 0.f;
#pragma unroll
        for (int w = 0; w < 8; ++w) t += red[w * 64 + tid];
        atomicAdd(&esum[tid], (double)t);
        __threadfence();
    }
    __syncthreads();
    if (tid == 0) {
        int t = atomicAdd(ticket, 1);
        isLast = (t == (int)gridDim.x - 1);
        __threadfence();
    }
    __syncthreads();

    // ---- last block computes the scalar loss (f64) ----
    if (isLast && tid < NE) {
        double v = atomicAdd(&esum[tid], 0.0);    // device-scope read
        double mean = v * (1.0 / 32768.0);
        double d  = mean - (1.0 / 64.0);
        double sq = d * d;
#pragma unroll
        for (int off = 32; off; off >>= 1) sq += __shfl_xor(sq, off);
        if (tid == 0) lossp[0] = (float)(sq * (1.0 / 64.0) * 0.01);
    }
}

extern "C" void kernel_launch(void* const* d_in, const int* in_sizes, int n_in,
                              void* d_out, int out_size, void* d_ws, size_t ws_size,
                              hipStream_t stream) {
    const float* x     = (const float*)d_in[0];   // [32768,1024]
    const float* gw    = (const float*)d_in[1];   // [64,1024]
    const float* nw    = (const float*)d_in[2];   // [64]
    const float* noise = (const float*)d_in[3];   // [32768,64]

    float* out0  = (float*)d_out;                       // [32768,64] gated weights
    float* out1  = out0 + (size_t)N_ROWS * NE;          // [32768,8] ids as f32
    float* lossp = out1 + (size_t)N_ROWS * KTOP;        // scalar loss

    double* esum   = (double*)d_ws;                     // [64]
    int*    ticket = (int*)((char*)d_ws + 512);

    hipMemsetAsync(d_ws, 0, 520, stream);
    moe_gate_kernel<<<N_ROWS / 64, 512, 0, stream>>>(x, gw, nw, noise,
                                                     out0, out1, lossp, esum, ticket);
}